// Round 6
// baseline (186.402 us; speedup 1.0000x reference)
//
#include <hip/hip_runtime.h>

#define IMG_H 512
#define IMG_W 512
#define N_IMG 32
#define ROWS  4                    // output rows per wave-band: 4096 waves = 4/SIMD
#define BANDS (IMG_H / ROWS)       // 128 bands per image
#define NPIX  (32.0f * 512.0f * 512.0f)

// ---- DPP lane shifts (verified R3-R5): wave_shr:1 / wave_shl:1 with
//      bound_ctrl zero-fill = free image-edge zero padding.
__device__ __forceinline__ float dl(float x) {   // lane i <- lane i-1, lane0 <- 0
    return __int_as_float(__builtin_amdgcn_update_dpp(
        0, __float_as_int(x), 0x138, 0xf, 0xf, true));
}
__device__ __forceinline__ float dr(float x) {   // lane i <- lane i+1, lane63 <- 0
    return __int_as_float(__builtin_amdgcn_update_dpp(
        0, __float_as_int(x), 0x130, 0xf, 0xf, true));
}

// Branch-free loads. EDGE=false: rows guaranteed in range, raw unconditional.
// EDGE=true: clamp row + wave-uniform select (I=0, T_raw=-1 -> normalizes to 0).
template<bool EDGE>
__device__ __forceinline__ void load8t(const float* __restrict__ ip,
                                       const float* __restrict__ tp,
                                       int r, int c0, float* I, float* T) {
    const int rc = EDGE ? min(max(r, 0), IMG_H - 1) : r;
    const float* irow = ip + (ptrdiff_t)rc * IMG_W + c0;
    const float* trow = tp + (ptrdiff_t)rc * IMG_W + c0;
    float4 a = *(const float4*)(irow);
    float4 b = *(const float4*)(irow + 4);
    float4 c = *(const float4*)(trow);
    float4 d = *(const float4*)(trow + 4);
    I[0]=a.x; I[1]=a.y; I[2]=a.z; I[3]=a.w;
    I[4]=b.x; I[5]=b.y; I[6]=b.z; I[7]=b.w;
    T[0]=c.x; T[1]=c.y; T[2]=c.z; T[3]=c.w;
    T[4]=d.x; T[5]=d.y; T[6]=d.z; T[7]=d.w;
    if (EDGE) {
        const bool v = (r >= 0) && (r < IMG_H);   // wave-uniform
        #pragma unroll
        for (int j = 0; j < 8; ++j) {
            I[j] = v ? I[j] : 0.0f;
            T[j] = v ? T[j] : -1.0f;
        }
    }
}

__device__ __forceinline__ void slide_lead(const float* LI, const float* LTr,
                                           float* vI, float* vT, float* vII,
                                           float* vTT, float* vIT) {
    #pragma unroll
    for (int j = 0; j < 8; ++j) {
        float li = LI[j];
        float lt = fmaf(LTr[j], 0.5f, 0.5f);
        vI[j]  += li;
        vT[j]  += lt;
        vII[j]  = fmaf(li, li, vII[j]);
        vTT[j]  = fmaf(lt, lt, vTT[j]);
        vIT[j]  = fmaf(li, lt, vIT[j]);
    }
}

__device__ __forceinline__ void slide_full(const float* LI, const float* LTr,
                                           const float* QI, const float* QTr,
                                           float* vI, float* vT, float* vII,
                                           float* vTT, float* vIT) {
    #pragma unroll
    for (int j = 0; j < 8; ++j) {
        float li = LI[j], qi = QI[j];
        float lt = fmaf(LTr[j], 0.5f, 0.5f);
        float qt = fmaf(QTr[j], 0.5f, 0.5f);
        float dI = li - qi, aI = li + qi;
        float dT = lt - qt, aT = lt + qt;
        vI[j]  += dI;
        vT[j]  += dT;
        vII[j]  = fmaf(dI, aI, vII[j]);
        vTT[j]  = fmaf(dT, aT, vTT[j]);
        vIT[j]  = fmaf(li, lt, vIT[j] - qi * qt);
    }
}

__device__ __forceinline__ float cc_of(float sI, float sT, float sII, float sTT, float sIT) {
    const float inv81 = 1.0f / 81.0f;
    float u     = sI * inv81;
    float w     = sT * inv81;
    float cross = fmaf(-u, sT, sIT);
    float iv    = fmaf(-u, sI, sII);
    float tv    = fmaf(-w, sT, sTT);
    float den   = fmaf(tv, iv, 1e-5f);
    return cross * cross * __builtin_amdgcn_rcpf(den);
}

// Horizontal 9-tap sums + cc; DPP halos computed INLINE at use sites
// (kills the 40-register L/R arrays -> keeps peak VGPR under 128).
__device__ __forceinline__ float hphase(const float* vI, const float* vT,
                                        const float* vII, const float* vTT,
                                        const float* vIT) {
    float s0 = ((dl(vI [4])+dl(vI [5]))+(dl(vI [6])+dl(vI [7]))) + ((vI [0]+vI [1])+(vI [2]+vI [3])) + vI [4];
    float s1 = ((dl(vT [4])+dl(vT [5]))+(dl(vT [6])+dl(vT [7]))) + ((vT [0]+vT [1])+(vT [2]+vT [3])) + vT [4];
    float s2 = ((dl(vII[4])+dl(vII[5]))+(dl(vII[6])+dl(vII[7]))) + ((vII[0]+vII[1])+(vII[2]+vII[3])) + vII[4];
    float s3 = ((dl(vTT[4])+dl(vTT[5]))+(dl(vTT[6])+dl(vTT[7]))) + ((vTT[0]+vTT[1])+(vTT[2]+vTT[3])) + vTT[4];
    float s4 = ((dl(vIT[4])+dl(vIT[5]))+(dl(vIT[6])+dl(vIT[7]))) + ((vIT[0]+vIT[1])+(vIT[2]+vIT[3])) + vIT[4];
    float part = cc_of(s0, s1, s2, s3, s4);

    #define HSTEP(e0,e1,e2,e3,e4) \
        s0 += (e0); s1 += (e1); s2 += (e2); s3 += (e3); s4 += (e4); \
        part += cc_of(s0, s1, s2, s3, s4);

    HSTEP(vI[5]-dl(vI[4]), vT[5]-dl(vT[4]), vII[5]-dl(vII[4]), vTT[5]-dl(vTT[4]), vIT[5]-dl(vIT[4]))     // j=1
    HSTEP(vI[6]-dl(vI[5]), vT[6]-dl(vT[5]), vII[6]-dl(vII[5]), vTT[6]-dl(vTT[5]), vIT[6]-dl(vIT[5]))     // j=2
    HSTEP(vI[7]-dl(vI[6]), vT[7]-dl(vT[6]), vII[7]-dl(vII[6]), vTT[7]-dl(vTT[6]), vIT[7]-dl(vIT[6]))     // j=3
    HSTEP(dr(vI[0])-dl(vI[7]), dr(vT[0])-dl(vT[7]), dr(vII[0])-dl(vII[7]),
          dr(vTT[0])-dl(vTT[7]), dr(vIT[0])-dl(vIT[7]))                                                  // j=4
    HSTEP(dr(vI[1])-vI[0], dr(vT[1])-vT[0], dr(vII[1])-vII[0], dr(vTT[1])-vTT[0], dr(vIT[1])-vIT[0])     // j=5
    HSTEP(dr(vI[2])-vI[1], dr(vT[2])-vT[1], dr(vII[2])-vII[1], dr(vTT[2])-vTT[1], dr(vIT[2])-vIT[1])     // j=6
    HSTEP(dr(vI[3])-vI[2], dr(vT[3])-vT[2], dr(vII[3])-vII[2], dr(vTT[3])-vTT[2], dr(vIT[3])-vIT[2])     // j=7
    #undef HSTEP
    return part;
}

// Whole band: compact rolling loops, branch-free bodies, named A/B ping-pong.
// Iter m (m=0..11): lead row r0+m-4; trail row r0+m-13 (active m>=9).
// H phase on m=8..11 -> output rows r0..r0+3.
template<bool EDGE>
__device__ __forceinline__ float band_body(const float* __restrict__ ip,
                                           const float* __restrict__ tp,
                                           int r0, int c0) {
    float vI[8] = {}, vT[8] = {}, vII[8] = {}, vTT[8] = {}, vIT[8] = {};
    float acc = 0.0f;

    float ALI[8], ALT[8], AQI[8], AQT[8];
    float BLI[8], BLT[8], BQI[8], BQT[8];

    load8t<EDGE>(ip, tp, r0 - 4, c0, ALI, ALT);          // lead(0)
    load8t<EDGE>(ip, tp, r0 - 3, c0, BLI, BLT);          // lead(1)

    // ---- ramp: iters 0..7 (rolling, prefetch distance 2 iters) ----
    #pragma unroll 1
    for (int p = 0; p < 4; ++p) {
        slide_lead(ALI, ALT, vI, vT, vII, vTT, vIT);     // iter 2p
        load8t<EDGE>(ip, tp, r0 - 2 + 2*p, c0, ALI, ALT);// lead(2p+2); p=3 -> lead(8)
        slide_lead(BLI, BLT, vI, vT, vII, vTT, vIT);     // iter 2p+1
        load8t<EDGE>(ip, tp, r0 - 1 + 2*p, c0, BLI, BLT);// lead(2p+3); p=3 -> lead(9)
    }

    // neutral trail for iter 8 (window not full yet): I=0, T_raw=-1 -> 0
    #pragma unroll
    for (int j = 0; j < 8; ++j) { AQI[j] = 0.0f; AQT[j] = -1.0f; }
    load8t<EDGE>(ip, tp, r0 - 4, c0, BQI, BQT);          // trail(9)

    // ---- hot: iters 8..11 (2 passes x 2 iters; p=1 prefetch is dead but
    //      keeps the body branch-free; rows stay in [r0-4, r0+9]) ----
    #pragma unroll 1
    for (int p = 0; p < 2; ++p) {
        slide_full(ALI, ALT, AQI, AQT, vI, vT, vII, vTT, vIT);   // iter 8+2p
        load8t<EDGE>(ip, tp, r0 + 6 + 2*p, c0, ALI, ALT);        // lead(10+2p)
        load8t<EDGE>(ip, tp, r0 - 3 + 2*p, c0, AQI, AQT);        // trail(10+2p)
        acc += hphase(vI, vT, vII, vTT, vIT);

        slide_full(BLI, BLT, BQI, BQT, vI, vT, vII, vTT, vIT);   // iter 9+2p
        load8t<EDGE>(ip, tp, r0 + 7 + 2*p, c0, BLI, BLT);        // lead(11+2p)
        load8t<EDGE>(ip, tp, r0 - 2 + 2*p, c0, BQI, BQT);        // trail(11+2p)
        acc += hphase(vI, vT, vII, vTT, vIT);
    }
    return acc;
}

__global__ __launch_bounds__(256, 4)   // force VGPR <= 128: 4 waves/SIMD
void cc_loss_kernel(const float* __restrict__ in, const float* __restrict__ tg,
                    float* __restrict__ out) {
    __shared__ float red[4];

    const int t    = threadIdx.x;
    const int w    = t >> 6;
    const int lane = t & 63;

    // XCD-chunked swizzle: each XCD owns 128 consecutive blocks = 4 images.
    const int bid  = blockIdx.x;                       // 0..1023
    const int bs   = (bid & 7) * 128 + (bid >> 3);     // bijective (1024 % 8 == 0)

    const int gband = bs * 4 + w;              // 0..4095
    const int b     = gband >> 7;              // image (128 bands each)
    const int band  = gband & 127;
    const int r0    = band * ROWS;
    const size_t base = (size_t)b * (IMG_H * IMG_W);
    const float* ip = in + base;
    const float* tp = tg + base;
    const int c0    = lane * 8;                // own image cols c0..c0+7

    // Interior bands touch rows r0-4 .. r0+9 -> need 1 <= band <= 125.
    float acc;
    if (band >= 1 && band <= 125) acc = band_body<false>(ip, tp, r0, c0);
    else                          acc = band_body<true >(ip, tp, r0, c0);

    // ---- reduction: wave shuffle, one barrier per block, one atomic ----
    #pragma unroll
    for (int off = 32; off > 0; off >>= 1) acc += __shfl_down(acc, off, 64);
    if (lane == 0) red[w] = acc;
    __syncthreads();
    if (t == 0)
        atomicAdd(out, (red[0] + red[1] + red[2] + red[3]) * (-1.0f / NPIX));
}

extern "C" void kernel_launch(void* const* d_in, const int* in_sizes, int n_in,
                              void* d_out, int out_size, void* d_ws, size_t ws_size,
                              hipStream_t stream) {
    const float* in = (const float*)d_in[0];
    const float* tg = (const float*)d_in[1];
    float* out = (float*)d_out;

    hipMemsetAsync(out, 0, sizeof(float), stream);
    dim3 grid(N_IMG * BANDS / 4);              // 1024 blocks x 4 wave-bands
    cc_loss_kernel<<<grid, 256, 0, stream>>>(in, tg, out);
}

// Round 7
// 117.309 us; speedup vs baseline: 1.5890x; 1.5890x over previous
//
#include <hip/hip_runtime.h>

#define IMG_H 512
#define IMG_W 512
#define N_IMG 32
#define ROWS  4                    // output rows per wave-band: 4096 waves = 4/SIMD
#define BANDS (IMG_H / ROWS)       // 128 bands per image
#define NPIX  (32.0f * 512.0f * 512.0f)

// ---- DPP lane shifts (verified R3-R6): wave_shr:1 / wave_shl:1 with
//      bound_ctrl zero-fill = free image-edge zero padding.
__device__ __forceinline__ float dl(float x) {   // lane i <- lane i-1, lane0 <- 0
    return __int_as_float(__builtin_amdgcn_update_dpp(
        0, __float_as_int(x), 0x138, 0xf, 0xf, true));
}
__device__ __forceinline__ float dr(float x) {   // lane i <- lane i+1, lane63 <- 0
    return __int_as_float(__builtin_amdgcn_update_dpp(
        0, __float_as_int(x), 0x130, 0xf, 0xf, true));
}

// Branch-free loads. EDGE=false: rows guaranteed in range, raw unconditional.
// EDGE=true: clamp row + wave-uniform select (I=0, T_raw=-1 -> normalizes to 0).
template<bool EDGE>
__device__ __forceinline__ void load8t(const float* __restrict__ ip,
                                       const float* __restrict__ tp,
                                       int r, int c0, float* I, float* T) {
    const int rc = EDGE ? min(max(r, 0), IMG_H - 1) : r;
    const float* irow = ip + (ptrdiff_t)rc * IMG_W + c0;
    const float* trow = tp + (ptrdiff_t)rc * IMG_W + c0;
    float4 a = *(const float4*)(irow);
    float4 b = *(const float4*)(irow + 4);
    float4 c = *(const float4*)(trow);
    float4 d = *(const float4*)(trow + 4);
    I[0]=a.x; I[1]=a.y; I[2]=a.z; I[3]=a.w;
    I[4]=b.x; I[5]=b.y; I[6]=b.z; I[7]=b.w;
    T[0]=c.x; T[1]=c.y; T[2]=c.z; T[3]=c.w;
    T[4]=d.x; T[5]=d.y; T[6]=d.z; T[7]=d.w;
    if (EDGE) {
        const bool v = (r >= 0) && (r < IMG_H);   // wave-uniform
        #pragma unroll
        for (int j = 0; j < 8; ++j) {
            I[j] = v ? I[j] : 0.0f;
            T[j] = v ? T[j] : -1.0f;
        }
    }
}

__device__ __forceinline__ void slide_lead(const float* LI, const float* LTr,
                                           float* vI, float* vT, float* vII,
                                           float* vTT, float* vIT) {
    #pragma unroll
    for (int j = 0; j < 8; ++j) {
        float li = LI[j];
        float lt = fmaf(LTr[j], 0.5f, 0.5f);
        vI[j]  += li;
        vT[j]  += lt;
        vII[j]  = fmaf(li, li, vII[j]);
        vTT[j]  = fmaf(lt, lt, vTT[j]);
        vIT[j]  = fmaf(li, lt, vIT[j]);
    }
}

__device__ __forceinline__ void slide_full(const float* LI, const float* LTr,
                                           const float* QI, const float* QTr,
                                           float* vI, float* vT, float* vII,
                                           float* vTT, float* vIT) {
    #pragma unroll
    for (int j = 0; j < 8; ++j) {
        float li = LI[j], qi = QI[j];
        float lt = fmaf(LTr[j], 0.5f, 0.5f);
        float qt = fmaf(QTr[j], 0.5f, 0.5f);
        float dI = li - qi, aI = li + qi;
        float dT = lt - qt, aT = lt + qt;
        vI[j]  += dI;
        vT[j]  += dT;
        vII[j]  = fmaf(dI, aI, vII[j]);
        vTT[j]  = fmaf(dT, aT, vTT[j]);
        vIT[j]  = fmaf(li, lt, vIT[j] - qi * qt);
    }
}

__device__ __forceinline__ float cc_of(float sI, float sT, float sII, float sTT, float sIT) {
    const float inv81 = 1.0f / 81.0f;
    float u     = sI * inv81;
    float w     = sT * inv81;
    float cross = fmaf(-u, sT, sIT);
    float iv    = fmaf(-u, sI, sII);
    float tv    = fmaf(-w, sT, sTT);
    float den   = fmaf(tv, iv, 1e-5f);
    return cross * cross * __builtin_amdgcn_rcpf(den);
}

// Horizontal 9-tap sums + cc; DPP halos inline (correctness-verified R6).
__device__ __forceinline__ float hphase(const float* vI, const float* vT,
                                        const float* vII, const float* vTT,
                                        const float* vIT) {
    float s0 = ((dl(vI [4])+dl(vI [5]))+(dl(vI [6])+dl(vI [7]))) + ((vI [0]+vI [1])+(vI [2]+vI [3])) + vI [4];
    float s1 = ((dl(vT [4])+dl(vT [5]))+(dl(vT [6])+dl(vT [7]))) + ((vT [0]+vT [1])+(vT [2]+vT [3])) + vT [4];
    float s2 = ((dl(vII[4])+dl(vII[5]))+(dl(vII[6])+dl(vII[7]))) + ((vII[0]+vII[1])+(vII[2]+vII[3])) + vII[4];
    float s3 = ((dl(vTT[4])+dl(vTT[5]))+(dl(vTT[6])+dl(vTT[7]))) + ((vTT[0]+vTT[1])+(vTT[2]+vTT[3])) + vTT[4];
    float s4 = ((dl(vIT[4])+dl(vIT[5]))+(dl(vIT[6])+dl(vIT[7]))) + ((vIT[0]+vIT[1])+(vIT[2]+vIT[3])) + vIT[4];
    float part = cc_of(s0, s1, s2, s3, s4);

    #define HSTEP(e0,e1,e2,e3,e4) \
        s0 += (e0); s1 += (e1); s2 += (e2); s3 += (e3); s4 += (e4); \
        part += cc_of(s0, s1, s2, s3, s4);

    HSTEP(vI[5]-dl(vI[4]), vT[5]-dl(vT[4]), vII[5]-dl(vII[4]), vTT[5]-dl(vTT[4]), vIT[5]-dl(vIT[4]))     // j=1
    HSTEP(vI[6]-dl(vI[5]), vT[6]-dl(vT[5]), vII[6]-dl(vII[5]), vTT[6]-dl(vTT[5]), vIT[6]-dl(vIT[5]))     // j=2
    HSTEP(vI[7]-dl(vI[6]), vT[7]-dl(vT[6]), vII[7]-dl(vII[6]), vTT[7]-dl(vTT[6]), vIT[7]-dl(vIT[6]))     // j=3
    HSTEP(dr(vI[0])-dl(vI[7]), dr(vT[0])-dl(vT[7]), dr(vII[0])-dl(vII[7]),
          dr(vTT[0])-dl(vTT[7]), dr(vIT[0])-dl(vIT[7]))                                                  // j=4
    HSTEP(dr(vI[1])-vI[0], dr(vT[1])-vT[0], dr(vII[1])-vII[0], dr(vTT[1])-vTT[0], dr(vIT[1])-vIT[0])     // j=5
    HSTEP(dr(vI[2])-vI[1], dr(vT[2])-vT[1], dr(vII[2])-vII[1], dr(vTT[2])-vTT[1], dr(vIT[2])-vIT[1])     // j=6
    HSTEP(dr(vI[3])-vI[2], dr(vT[3])-vT[2], dr(vII[3])-vII[2], dr(vTT[3])-vTT[2], dr(vIT[3])-vIT[2])     // j=7
    #undef HSTEP
    return part;
}

// Whole band, SINGLE-BUFFERED (occupancy > per-wave ILP at 4 waves/SIMD).
// Iter m=0..11: lead row r0+m-4; trail row r0+m-13 (active m>=9);
// hphase on m=8..11 -> output rows r0..r0+3.  (Indexing verified R6.)
template<bool EDGE>
__device__ __forceinline__ float band_body(const float* __restrict__ ip,
                                           const float* __restrict__ tp,
                                           int r0, int c0) {
    float vI[8] = {}, vT[8] = {}, vII[8] = {}, vTT[8] = {}, vIT[8] = {};
    float LI[8], LT[8], QI[8], QT[8];
    float acc = 0.0f;

    // ---- ramp: iters 0..7 (rows r0-4 .. r0+3), rolling, branch-free ----
    #pragma unroll 1
    for (int m = 0; m < 8; ++m) {
        load8t<EDGE>(ip, tp, r0 - 4 + m, c0, LI, LT);
        slide_lead(LI, LT, vI, vT, vII, vTT, vIT);
    }

    // ---- peeled m=8: window full (rows r0-4..r0+4), no trail yet ----
    load8t<EDGE>(ip, tp, r0 + 4, c0, LI, LT);
    slide_lead(LI, LT, vI, vT, vII, vTT, vIT);
    acc += hphase(vI, vT, vII, vTT, vIT);

    // ---- hot: iters m=9..11, rolling, branch-free ----
    #pragma unroll 1
    for (int m = 9; m < 12; ++m) {
        load8t<EDGE>(ip, tp, r0 + m - 4,  c0, LI, LT);   // lead
        load8t<EDGE>(ip, tp, r0 + m - 13, c0, QI, QT);   // trail
        slide_full(LI, LT, QI, QT, vI, vT, vII, vTT, vIT);
        acc += hphase(vI, vT, vII, vTT, vIT);
    }
    return acc;
}

__global__ __launch_bounds__(256)      // NO min-occupancy coercion (R6 lesson)
void cc_loss_kernel(const float* __restrict__ in, const float* __restrict__ tg,
                    float* __restrict__ out) {
    __shared__ float red[4];

    const int t    = threadIdx.x;
    const int w    = t >> 6;
    const int lane = t & 63;

    // XCD-chunked swizzle: each XCD owns 128 consecutive blocks = 4 images.
    const int bid  = blockIdx.x;                       // 0..1023
    const int bs   = (bid & 7) * 128 + (bid >> 3);     // bijective (1024 % 8 == 0)

    const int gband = bs * 4 + w;              // 0..4095
    const int b     = gband >> 7;              // image (128 bands each)
    const int band  = gband & 127;
    const int r0    = band * ROWS;
    const size_t base = (size_t)b * (IMG_H * IMG_W);
    const float* ip = in + base;
    const float* tp = tg + base;
    const int c0    = lane * 8;                // own image cols c0..c0+7

    // Interior bands touch rows r0-4 .. r0+7 -> need 1 <= band <= 126.
    float acc;
    if (band >= 1 && band <= 126) acc = band_body<false>(ip, tp, r0, c0);
    else                          acc = band_body<true >(ip, tp, r0, c0);

    // ---- reduction: wave shuffle, one barrier per block, one atomic ----
    #pragma unroll
    for (int off = 32; off > 0; off >>= 1) acc += __shfl_down(acc, off, 64);
    if (lane == 0) red[w] = acc;
    __syncthreads();
    if (t == 0)
        atomicAdd(out, (red[0] + red[1] + red[2] + red[3]) * (-1.0f / NPIX));
}

extern "C" void kernel_launch(void* const* d_in, const int* in_sizes, int n_in,
                              void* d_out, int out_size, void* d_ws, size_t ws_size,
                              hipStream_t stream) {
    const float* in = (const float*)d_in[0];
    const float* tg = (const float*)d_in[1];
    float* out = (float*)d_out;

    hipMemsetAsync(out, 0, sizeof(float), stream);
    dim3 grid(N_IMG * BANDS / 4);              // 1024 blocks x 4 wave-bands
    cc_loss_kernel<<<grid, 256, 0, stream>>>(in, tg, out);
}

// Round 10
// 110.682 us; speedup vs baseline: 1.6841x; 1.0599x over previous
//
#include <hip/hip_runtime.h>

#define IMG_H 512
#define IMG_W 512
#define N_IMG 32
#define ROWS  8                    // output rows per wave-band (R4-verified regime)
#define BANDS (IMG_H / ROWS)       // 64 bands per image
#define NPIX  (32.0f * 512.0f * 512.0f)

// ---- DPP lane shifts (verified R3-R7): wave_shr:1 / wave_shl:1 with
//      bound_ctrl zero-fill = free image-edge zero padding.
__device__ __forceinline__ float dl(float x) {   // lane i <- lane i-1, lane0 <- 0
    return __int_as_float(__builtin_amdgcn_update_dpp(
        0, __float_as_int(x), 0x138, 0xf, 0xf, true));
}
__device__ __forceinline__ float dr(float x) {   // lane i <- lane i+1, lane63 <- 0
    return __int_as_float(__builtin_amdgcn_update_dpp(
        0, __float_as_int(x), 0x130, 0xf, 0xf, true));
}

// Raw loads (R4-verified). Branch kept deliberately: common path has NO
// post-load ALU, so prefetched loads stay in flight (R3 lesson).
// Out-of-range rows: I = 0, T_raw = -1 so fmaf(-1,0.5,0.5) = 0 at consumption.
__device__ __forceinline__ void load8raw(const float* __restrict__ ip,
                                         const float* __restrict__ tp,
                                         int r, int c0, float* I, float* T) {
    if (r >= 0 && r < IMG_H) {
        const float* irow = ip + (ptrdiff_t)r * IMG_W + c0;
        const float* trow = tp + (ptrdiff_t)r * IMG_W + c0;
        float4 a = *(const float4*)(irow);
        float4 b = *(const float4*)(irow + 4);
        float4 c = *(const float4*)(trow);
        float4 d = *(const float4*)(trow + 4);
        I[0]=a.x; I[1]=a.y; I[2]=a.z; I[3]=a.w;
        I[4]=b.x; I[5]=b.y; I[6]=b.z; I[7]=b.w;
        T[0]=c.x; T[1]=c.y; T[2]=c.z; T[3]=c.w;
        T[4]=d.x; T[5]=d.y; T[6]=d.z; T[7]=d.w;
    } else {
        #pragma unroll
        for (int j = 0; j < 8; ++j) { I[j] = 0.0f; T[j] = -1.0f; }
    }
}

// Vertical slides; T normalized at consume site (R4/R7-verified).
__device__ __forceinline__ void slide_lead(const float* LI, const float* LTr,
                                           float* vI, float* vT, float* vII,
                                           float* vTT, float* vIT) {
    #pragma unroll
    for (int j = 0; j < 8; ++j) {
        float li = LI[j];
        float lt = fmaf(LTr[j], 0.5f, 0.5f);
        vI[j]  += li;
        vT[j]  += lt;
        vII[j]  = fmaf(li, li, vII[j]);
        vTT[j]  = fmaf(lt, lt, vTT[j]);
        vIT[j]  = fmaf(li, lt, vIT[j]);
    }
}

__device__ __forceinline__ void slide_full(const float* LI, const float* LTr,
                                           const float* QI, const float* QTr,
                                           float* vI, float* vT, float* vII,
                                           float* vTT, float* vIT) {
    #pragma unroll
    for (int j = 0; j < 8; ++j) {
        float li = LI[j], qi = QI[j];
        float lt = fmaf(LTr[j], 0.5f, 0.5f);
        float qt = fmaf(QTr[j], 0.5f, 0.5f);
        float dI = li - qi, aI = li + qi;
        float dT = lt - qt, aT = lt + qt;
        vI[j]  += dI;
        vT[j]  += dT;
        vII[j]  = fmaf(dI, aI, vII[j]);
        vTT[j]  = fmaf(dT, aT, vTT[j]);
        vIT[j]  = fmaf(li, lt, vIT[j] - qi * qt);
    }
}

__device__ __forceinline__ float cc_of(float sI, float sT, float sII, float sTT, float sIT) {
    const float inv81 = 1.0f / 81.0f;
    float u     = sI * inv81;
    float w     = sT * inv81;
    float cross = fmaf(-u, sT, sIT);
    float iv    = fmaf(-u, sI, sII);
    float tv    = fmaf(-w, sT, sTT);
    float den   = fmaf(tv, iv, 1e-5f);
    return cross * cross * __builtin_amdgcn_rcpf(den);
}

// Horizontal 9-tap sums + cc; inline DPP halos (verified R6/R7: lower
// register pressure than the L/R-array version).
__device__ __forceinline__ float hphase(const float* vI, const float* vT,
                                        const float* vII, const float* vTT,
                                        const float* vIT) {
    float s0 = ((dl(vI [4])+dl(vI [5]))+(dl(vI [6])+dl(vI [7]))) + ((vI [0]+vI [1])+(vI [2]+vI [3])) + vI [4];
    float s1 = ((dl(vT [4])+dl(vT [5]))+(dl(vT [6])+dl(vT [7]))) + ((vT [0]+vT [1])+(vT [2]+vT [3])) + vT [4];
    float s2 = ((dl(vII[4])+dl(vII[5]))+(dl(vII[6])+dl(vII[7]))) + ((vII[0]+vII[1])+(vII[2]+vII[3])) + vII[4];
    float s3 = ((dl(vTT[4])+dl(vTT[5]))+(dl(vTT[6])+dl(vTT[7]))) + ((vTT[0]+vTT[1])+(vTT[2]+vTT[3])) + vTT[4];
    float s4 = ((dl(vIT[4])+dl(vIT[5]))+(dl(vIT[6])+dl(vIT[7]))) + ((vIT[0]+vIT[1])+(vIT[2]+vIT[3])) + vIT[4];
    float part = cc_of(s0, s1, s2, s3, s4);

    #define HSTEP(e0,e1,e2,e3,e4) \
        s0 += (e0); s1 += (e1); s2 += (e2); s3 += (e3); s4 += (e4); \
        part += cc_of(s0, s1, s2, s3, s4);

    HSTEP(vI[5]-dl(vI[4]), vT[5]-dl(vT[4]), vII[5]-dl(vII[4]), vTT[5]-dl(vTT[4]), vIT[5]-dl(vIT[4]))     // j=1
    HSTEP(vI[6]-dl(vI[5]), vT[6]-dl(vT[5]), vII[6]-dl(vII[5]), vTT[6]-dl(vTT[5]), vIT[6]-dl(vIT[5]))     // j=2
    HSTEP(vI[7]-dl(vI[6]), vT[7]-dl(vT[6]), vII[7]-dl(vII[6]), vTT[7]-dl(vTT[6]), vIT[7]-dl(vIT[6]))     // j=3
    HSTEP(dr(vI[0])-dl(vI[7]), dr(vT[0])-dl(vT[7]), dr(vII[0])-dl(vII[7]),
          dr(vTT[0])-dl(vTT[7]), dr(vIT[0])-dl(vIT[7]))                                                  // j=4
    HSTEP(dr(vI[1])-vI[0], dr(vT[1])-vT[0], dr(vII[1])-vII[0], dr(vTT[1])-vTT[0], dr(vIT[1])-vIT[0])     // j=5
    HSTEP(dr(vI[2])-vI[1], dr(vT[2])-vT[1], dr(vII[2])-vII[1], dr(vTT[2])-vTT[1], dr(vIT[2])-vIT[1])     // j=6
    HSTEP(dr(vI[3])-vI[2], dr(vT[3])-vT[2], dr(vII[3])-vII[2], dr(vTT[3])-vTT[2], dr(vIT[3])-vIT[2])     // j=7
    #undef HSTEP
    return part;
}

__global__ __launch_bounds__(256)
void cc_loss_kernel(const float* __restrict__ in, const float* __restrict__ tg,
                    float* __restrict__ out) {
    __shared__ float red[4];

    const int t    = threadIdx.x;
    const int w    = t >> 6;
    const int lane = t & 63;

    // XCD-chunked swizzle (R4-verified): each XCD owns 64 consecutive blocks.
    const int bid  = blockIdx.x;                       // 0..511
    const int bs   = (bid & 7) * 64 + (bid >> 3);      // bijective (512 % 8 == 0)

    const int gband = bs * 4 + w;              // 0..2047
    const int b     = gband >> 6;              // image (64 bands each)
    const int band  = gband & 63;
    const int r0    = band * ROWS;
    const size_t base = (size_t)b * (IMG_H * IMG_W);
    const float* ip = in + base;
    const float* tp = tg + base;
    const int c0    = lane * 8;                // own image cols c0..c0+7

    float vI[8] = {}, vT[8] = {}, vII[8] = {}, vTT[8] = {}, vIT[8] = {};
    float acc = 0.0f;

    // Named buffers only (R4-verified compile mode).
    float ALI[8], ALT[8], AQI[8], AQT[8];
    float BLI[8], BLT[8], BQI[8], BQT[8];
    float CLI[8], CLT[8], DLI[8], DLT[8];

    // ---- ramp: add window rows r0-4 .. r0+3 (iters 0..7), depth-4 pipeline
    //      (byte-level R4) ----
    load8raw(ip, tp, r0 - 4, c0, ALI, ALT);
    load8raw(ip, tp, r0 - 3, c0, BLI, BLT);
    load8raw(ip, tp, r0 - 2, c0, CLI, CLT);
    load8raw(ip, tp, r0 - 1, c0, DLI, DLT);

    slide_lead(ALI, ALT, vI, vT, vII, vTT, vIT);       // iter 0: r0-4
    load8raw(ip, tp, r0 + 0, c0, ALI, ALT);
    slide_lead(BLI, BLT, vI, vT, vII, vTT, vIT);       // iter 1: r0-3
    load8raw(ip, tp, r0 + 1, c0, BLI, BLT);
    slide_lead(CLI, CLT, vI, vT, vII, vTT, vIT);       // iter 2: r0-2
    load8raw(ip, tp, r0 + 2, c0, CLI, CLT);
    slide_lead(DLI, DLT, vI, vT, vII, vTT, vIT);       // iter 3: r0-1
    load8raw(ip, tp, r0 + 3, c0, DLI, DLT);

    slide_lead(ALI, ALT, vI, vT, vII, vTT, vIT);       // iter 4: r0+0
    load8raw(ip, tp, r0 + 4, c0, ALI, ALT);            // lead(8)
    slide_lead(BLI, BLT, vI, vT, vII, vTT, vIT);       // iter 5: r0+1
    load8raw(ip, tp, r0 + 5, c0, BLI, BLT);            // lead(9)
    load8raw(ip, tp, r0 - 4, c0, BQI, BQT);            // trail(9)
    slide_lead(CLI, CLT, vI, vT, vII, vTT, vIT);       // iter 6: r0+2
    slide_lead(DLI, DLT, vI, vT, vII, vTT, vIT);       // iter 7: r0+3

    // Neutral trail for iter 8 (R6-verified trick): I=0, T_raw=-1 -> q terms
    // are exactly 0, so slide_full == slide_lead. Removes the p==0 branch.
    #pragma unroll
    for (int j = 0; j < 8; ++j) { AQI[j] = 0.0f; AQT[j] = -1.0f; }

    // ---- hot: iter pairs (8,9),(10,11),(12,13),(14,15); rolling ping-pong
    //      (R4-verified indexing), branch-free except uniform p<3 guard ----
    #pragma unroll 1
    for (int p = 0; p < 4; ++p) {
        const int k = 8 + 2 * p;

        slide_full(ALI, ALT, AQI, AQT, vI, vT, vII, vTT, vIT);   // iter k
        if (p < 3) {
            load8raw(ip, tp, r0 + k - 2,  c0, ALI, ALT);         // lead(k+2)
            load8raw(ip, tp, r0 + k - 11, c0, AQI, AQT);         // trail(k+2)
        }
        acc += hphase(vI, vT, vII, vTT, vIT);

        slide_full(BLI, BLT, BQI, BQT, vI, vT, vII, vTT, vIT);   // iter k+1
        if (p < 3) {
            load8raw(ip, tp, r0 + k - 1,  c0, BLI, BLT);         // lead(k+3)
            load8raw(ip, tp, r0 + k - 10, c0, BQI, BQT);         // trail(k+3)
        }
        acc += hphase(vI, vT, vII, vTT, vIT);
    }

    // ---- reduction: wave shuffle, one barrier per block, one atomic ----
    #pragma unroll
    for (int off = 32; off > 0; off >>= 1) acc += __shfl_down(acc, off, 64);
    if (lane == 0) red[w] = acc;
    __syncthreads();
    if (t == 0)
        atomicAdd(out, (red[0] + red[1] + red[2] + red[3]) * (-1.0f / NPIX));
}

extern "C" void kernel_launch(void* const* d_in, const int* in_sizes, int n_in,
                              void* d_out, int out_size, void* d_ws, size_t ws_size,
                              hipStream_t stream) {
    const float* in = (const float*)d_in[0];
    const float* tg = (const float*)d_in[1];
    float* out = (float*)d_out;

    hipMemsetAsync(out, 0, sizeof(float), stream);
    dim3 grid(N_IMG * BANDS / 4);              // 512 blocks x 4 wave-bands
    cc_loss_kernel<<<grid, 256, 0, stream>>>(in, tg, out);
}

// Round 11
// 109.030 us; speedup vs baseline: 1.7096x; 1.0151x over previous
//
#include <hip/hip_runtime.h>

#define IMG_H 512
#define IMG_W 512
#define N_IMG 32
#define ROWS  8                    // output rows per wave-band (verified regime)
#define BANDS (IMG_H / ROWS)       // 64 bands per image
#define NPIX  (32.0f * 512.0f * 512.0f)

// ---- DPP lane shifts (verified R3-R10): wave_shr:1 / wave_shl:1 with
//      bound_ctrl zero-fill = free image-edge zero padding.
__device__ __forceinline__ float dl(float x) {   // lane i <- lane i-1, lane0 <- 0
    return __int_as_float(__builtin_amdgcn_update_dpp(
        0, __float_as_int(x), 0x138, 0xf, 0xf, true));
}
__device__ __forceinline__ float dr(float x) {   // lane i <- lane i+1, lane63 <- 0
    return __int_as_float(__builtin_amdgcn_update_dpp(
        0, __float_as_int(x), 0x130, 0xf, 0xf, true));
}

// Branch-free loads (verified R5/R7). EDGE=false: pure unconditional loads in
// one basic block -> exact counted vmcnt, maximal load clustering.
// EDGE=true: clamp row + wave-uniform select (I=0, t_raw=-1 -> normalizes to 0).
template<bool EDGE>
__device__ __forceinline__ void load8t(const float* __restrict__ ip,
                                       const float* __restrict__ tp,
                                       int r, int c0, float* I, float* T) {
    const int rc = EDGE ? min(max(r, 0), IMG_H - 1) : r;
    const float* irow = ip + (ptrdiff_t)rc * IMG_W + c0;
    const float* trow = tp + (ptrdiff_t)rc * IMG_W + c0;
    float4 a = *(const float4*)(irow);
    float4 b = *(const float4*)(irow + 4);
    float4 c = *(const float4*)(trow);
    float4 d = *(const float4*)(trow + 4);
    I[0]=a.x; I[1]=a.y; I[2]=a.z; I[3]=a.w;
    I[4]=b.x; I[5]=b.y; I[6]=b.z; I[7]=b.w;
    T[0]=c.x; T[1]=c.y; T[2]=c.z; T[3]=c.w;
    T[4]=d.x; T[5]=d.y; T[6]=d.z; T[7]=d.w;
    if (EDGE) {
        const bool v = (r >= 0) && (r < IMG_H);   // wave-uniform
        #pragma unroll
        for (int j = 0; j < 8; ++j) {
            I[j] = v ? I[j] : 0.0f;
            T[j] = v ? T[j] : -1.0f;
        }
    }
}

// Vertical slides; T normalized at consume site (verified R4/R7/R10).
__device__ __forceinline__ void slide_lead(const float* LI, const float* LTr,
                                           float* vI, float* vT, float* vII,
                                           float* vTT, float* vIT) {
    #pragma unroll
    for (int j = 0; j < 8; ++j) {
        float li = LI[j];
        float lt = fmaf(LTr[j], 0.5f, 0.5f);
        vI[j]  += li;
        vT[j]  += lt;
        vII[j]  = fmaf(li, li, vII[j]);
        vTT[j]  = fmaf(lt, lt, vTT[j]);
        vIT[j]  = fmaf(li, lt, vIT[j]);
    }
}

__device__ __forceinline__ void slide_full(const float* LI, const float* LTr,
                                           const float* QI, const float* QTr,
                                           float* vI, float* vT, float* vII,
                                           float* vTT, float* vIT) {
    #pragma unroll
    for (int j = 0; j < 8; ++j) {
        float li = LI[j], qi = QI[j];
        float lt = fmaf(LTr[j], 0.5f, 0.5f);
        float qt = fmaf(QTr[j], 0.5f, 0.5f);
        float dI = li - qi, aI = li + qi;
        float dT = lt - qt, aT = lt + qt;
        vI[j]  += dI;
        vT[j]  += dT;
        vII[j]  = fmaf(dI, aI, vII[j]);
        vTT[j]  = fmaf(dT, aT, vTT[j]);
        vIT[j]  = fmaf(li, lt, vIT[j] - qi * qt);
    }
}

__device__ __forceinline__ float cc_of(float sI, float sT, float sII, float sTT, float sIT) {
    const float inv81 = 1.0f / 81.0f;
    float u     = sI * inv81;
    float w     = sT * inv81;
    float cross = fmaf(-u, sT, sIT);
    float iv    = fmaf(-u, sI, sII);
    float tv    = fmaf(-w, sT, sTT);
    float den   = fmaf(tv, iv, 1e-5f);
    return cross * cross * __builtin_amdgcn_rcpf(den);
}

// Horizontal 9-tap sums + cc; inline DPP halos (verified R6/R7/R10).
__device__ __forceinline__ float hphase(const float* vI, const float* vT,
                                        const float* vII, const float* vTT,
                                        const float* vIT) {
    float s0 = ((dl(vI [4])+dl(vI [5]))+(dl(vI [6])+dl(vI [7]))) + ((vI [0]+vI [1])+(vI [2]+vI [3])) + vI [4];
    float s1 = ((dl(vT [4])+dl(vT [5]))+(dl(vT [6])+dl(vT [7]))) + ((vT [0]+vT [1])+(vT [2]+vT [3])) + vT [4];
    float s2 = ((dl(vII[4])+dl(vII[5]))+(dl(vII[6])+dl(vII[7]))) + ((vII[0]+vII[1])+(vII[2]+vII[3])) + vII[4];
    float s3 = ((dl(vTT[4])+dl(vTT[5]))+(dl(vTT[6])+dl(vTT[7]))) + ((vTT[0]+vTT[1])+(vTT[2]+vTT[3])) + vTT[4];
    float s4 = ((dl(vIT[4])+dl(vIT[5]))+(dl(vIT[6])+dl(vIT[7]))) + ((vIT[0]+vIT[1])+(vIT[2]+vIT[3])) + vIT[4];
    float part = cc_of(s0, s1, s2, s3, s4);

    #define HSTEP(e0,e1,e2,e3,e4) \
        s0 += (e0); s1 += (e1); s2 += (e2); s3 += (e3); s4 += (e4); \
        part += cc_of(s0, s1, s2, s3, s4);

    HSTEP(vI[5]-dl(vI[4]), vT[5]-dl(vT[4]), vII[5]-dl(vII[4]), vTT[5]-dl(vTT[4]), vIT[5]-dl(vIT[4]))     // j=1
    HSTEP(vI[6]-dl(vI[5]), vT[6]-dl(vT[5]), vII[6]-dl(vII[5]), vTT[6]-dl(vTT[5]), vIT[6]-dl(vIT[5]))     // j=2
    HSTEP(vI[7]-dl(vI[6]), vT[7]-dl(vT[6]), vII[7]-dl(vII[6]), vTT[7]-dl(vTT[6]), vIT[7]-dl(vIT[6]))     // j=3
    HSTEP(dr(vI[0])-dl(vI[7]), dr(vT[0])-dl(vT[7]), dr(vII[0])-dl(vII[7]),
          dr(vTT[0])-dl(vTT[7]), dr(vIT[0])-dl(vIT[7]))                                                  // j=4
    HSTEP(dr(vI[1])-vI[0], dr(vT[1])-vT[0], dr(vII[1])-vII[0], dr(vTT[1])-vTT[0], dr(vIT[1])-vIT[0])     // j=5
    HSTEP(dr(vI[2])-vI[1], dr(vT[2])-vT[1], dr(vII[2])-vII[1], dr(vTT[2])-vTT[1], dr(vIT[2])-vIT[1])     // j=6
    HSTEP(dr(vI[3])-vI[2], dr(vT[3])-vT[2], dr(vII[3])-vII[2], dr(vTT[3])-vTT[2], dr(vIT[3])-vIT[2])     // j=7
    #undef HSTEP
    return part;
}

// Band body: depth-6 lead ring (A..F) + 2 trail slots (Q0/Q1), fully
// straight-line -- every load in ONE basic block so hipcc emits exact
// counted vmcnt and ~24 dwordx4 stay in flight per wave.
// Iter m=0..15: lead(m)=row r0+m-4 in slot (m%6); trail(m)=row r0+m-13
// (m>=9) in slot Q[(m&1)^1... alternating]; hphase on m=8..15 -> rows r0..r0+7.
template<bool EDGE>
__device__ __forceinline__ float band_body(const float* __restrict__ ip,
                                           const float* __restrict__ tp,
                                           int r0, int c0) {
    float vI[8] = {}, vT[8] = {}, vII[8] = {}, vTT[8] = {}, vIT[8] = {};
    float acc = 0.0f;

    float AI[8], AT[8], BI[8], BT[8], CI[8], CT[8];
    float DI[8], DT[8], EI[8], ET[8], FI[8], FT[8];
    float QI0[8], QT0[8], QI1[8], QT1[8];

    // prologue: leads 0..5 (rows r0-4 .. r0+1), 24 dwordx4 in flight
    load8t<EDGE>(ip, tp, r0 - 4, c0, AI, AT);
    load8t<EDGE>(ip, tp, r0 - 3, c0, BI, BT);
    load8t<EDGE>(ip, tp, r0 - 2, c0, CI, CT);
    load8t<EDGE>(ip, tp, r0 - 1, c0, DI, DT);
    load8t<EDGE>(ip, tp, r0 + 0, c0, EI, ET);
    load8t<EDGE>(ip, tp, r0 + 1, c0, FI, FT);

    // ramp m=0..7: consume slot, re-issue lead(m+6) into same slot
    slide_lead(AI, AT, vI, vT, vII, vTT, vIT);   // m=0: row r0-4
    load8t<EDGE>(ip, tp, r0 + 2, c0, AI, AT);    //      lead(6)
    slide_lead(BI, BT, vI, vT, vII, vTT, vIT);   // m=1: row r0-3
    load8t<EDGE>(ip, tp, r0 + 3, c0, BI, BT);    //      lead(7)
    slide_lead(CI, CT, vI, vT, vII, vTT, vIT);   // m=2: row r0-2
    load8t<EDGE>(ip, tp, r0 + 4, c0, CI, CT);    //      lead(8)
    slide_lead(DI, DT, vI, vT, vII, vTT, vIT);   // m=3: row r0-1
    load8t<EDGE>(ip, tp, r0 + 5, c0, DI, DT);    //      lead(9)
    slide_lead(EI, ET, vI, vT, vII, vTT, vIT);   // m=4: row r0+0
    load8t<EDGE>(ip, tp, r0 + 6, c0, EI, ET);    //      lead(10)
    slide_lead(FI, FT, vI, vT, vII, vTT, vIT);   // m=5: row r0+1
    load8t<EDGE>(ip, tp, r0 + 7, c0, FI, FT);    //      lead(11)
    slide_lead(AI, AT, vI, vT, vII, vTT, vIT);   // m=6: row r0+2
    load8t<EDGE>(ip, tp, r0 + 8, c0, AI, AT);    //      lead(12)
    slide_lead(BI, BT, vI, vT, vII, vTT, vIT);   // m=7: row r0+3
    load8t<EDGE>(ip, tp, r0 + 9, c0, BI, BT);    //      lead(13)
    load8t<EDGE>(ip, tp, r0 - 4, c0, QI0, QT0);  //      trail(9)

    // m=8: window full (rows r0-4..r0+4), first output row r0
    slide_lead(CI, CT, vI, vT, vII, vTT, vIT);   // m=8: row r0+4
    load8t<EDGE>(ip, tp, r0 + 10, c0, CI, CT);   //      lead(14)
    load8t<EDGE>(ip, tp, r0 - 3,  c0, QI1, QT1); //      trail(10)
    acc += hphase(vI, vT, vII, vTT, vIT);        // -> r0

    slide_full(DI, DT, QI0, QT0, vI, vT, vII, vTT, vIT);  // m=9: +r0+5 -r0-4
    load8t<EDGE>(ip, tp, r0 + 11, c0, DI, DT);   //      lead(15)
    load8t<EDGE>(ip, tp, r0 - 2,  c0, QI0, QT0); //      trail(11)
    acc += hphase(vI, vT, vII, vTT, vIT);        // -> r0+1

    slide_full(EI, ET, QI1, QT1, vI, vT, vII, vTT, vIT);  // m=10: +r0+6 -r0-3
    load8t<EDGE>(ip, tp, r0 - 1, c0, QI1, QT1);  //      trail(12)
    acc += hphase(vI, vT, vII, vTT, vIT);        // -> r0+2

    slide_full(FI, FT, QI0, QT0, vI, vT, vII, vTT, vIT);  // m=11: +r0+7 -r0-2
    load8t<EDGE>(ip, tp, r0 + 0, c0, QI0, QT0);  //      trail(13)
    acc += hphase(vI, vT, vII, vTT, vIT);        // -> r0+3

    slide_full(AI, AT, QI1, QT1, vI, vT, vII, vTT, vIT);  // m=12: +r0+8 -r0-1
    load8t<EDGE>(ip, tp, r0 + 1, c0, QI1, QT1);  //      trail(14)
    acc += hphase(vI, vT, vII, vTT, vIT);        // -> r0+4

    slide_full(BI, BT, QI0, QT0, vI, vT, vII, vTT, vIT);  // m=13: +r0+9 -r0+0
    load8t<EDGE>(ip, tp, r0 + 2, c0, QI0, QT0);  //      trail(15)
    acc += hphase(vI, vT, vII, vTT, vIT);        // -> r0+5

    slide_full(CI, CT, QI1, QT1, vI, vT, vII, vTT, vIT);  // m=14: +r0+10 -r0+1
    acc += hphase(vI, vT, vII, vTT, vIT);        // -> r0+6

    slide_full(DI, DT, QI0, QT0, vI, vT, vII, vTT, vIT);  // m=15: +r0+11 -r0+2
    acc += hphase(vI, vT, vII, vTT, vIT);        // -> r0+7

    return acc;
}

__global__ __launch_bounds__(256)      // no min-occupancy coercion (R6 lesson);
void cc_loss_kernel(const float* __restrict__ in, const float* __restrict__ tg,
                    float* __restrict__ out) {
    // grid-limited to 2 waves/SIMD -> VGPR up to 256 is free; spend on MLP.
    __shared__ float red[4];

    const int t    = threadIdx.x;
    const int w    = t >> 6;
    const int lane = t & 63;

    // XCD-chunked swizzle (verified R4/R10): each XCD owns 64 consecutive
    // blocks = 4 whole images.
    const int bid  = blockIdx.x;                       // 0..511
    const int bs   = (bid & 7) * 64 + (bid >> 3);      // bijective (512 % 8 == 0)

    const int gband = bs * 4 + w;              // 0..2047
    const int b     = gband >> 6;              // image (64 bands each)
    const int band  = gband & 63;
    const int r0    = band * ROWS;
    const size_t base = (size_t)b * (IMG_H * IMG_W);
    const float* ip = in + base;
    const float* tp = tg + base;
    const int c0    = lane * 8;                // own image cols c0..c0+7

    // Interior bands touch rows r0-4 .. r0+11 -> need 1 <= band <= 62.
    float acc;
    if (band >= 1 && band <= 62) acc = band_body<false>(ip, tp, r0, c0);
    else                         acc = band_body<true >(ip, tp, r0, c0);

    // ---- reduction: wave shuffle, one barrier per block, one atomic ----
    #pragma unroll
    for (int off = 32; off > 0; off >>= 1) acc += __shfl_down(acc, off, 64);
    if (lane == 0) red[w] = acc;
    __syncthreads();
    if (t == 0)
        atomicAdd(out, (red[0] + red[1] + red[2] + red[3]) * (-1.0f / NPIX));
}

extern "C" void kernel_launch(void* const* d_in, const int* in_sizes, int n_in,
                              void* d_out, int out_size, void* d_ws, size_t ws_size,
                              hipStream_t stream) {
    const float* in = (const float*)d_in[0];
    const float* tg = (const float*)d_in[1];
    float* out = (float*)d_out;

    hipMemsetAsync(out, 0, sizeof(float), stream);
    dim3 grid(N_IMG * BANDS / 4);              // 512 blocks x 4 wave-bands
    cc_loss_kernel<<<grid, 256, 0, stream>>>(in, tg, out);
}

// Round 12
// 103.008 us; speedup vs baseline: 1.8096x; 1.0585x over previous
//
#include <hip/hip_runtime.h>

#define IMG_H 512
#define IMG_W 512
#define N_IMG 32
#define ROWS  8                    // output rows per wave-band
#define BANDS (IMG_H / ROWS)       // 64 bands per image
#define NPIX  (32.0f * 512.0f * 512.0f)

// ---- DPP lane shifts (verified R3-R11): wave_shr:1 / wave_shl:1 with
//      bound_ctrl zero-fill = free image-edge zero padding.
__device__ __forceinline__ float dl(float x) {   // lane i <- lane i-1, lane0 <- 0
    return __int_as_float(__builtin_amdgcn_update_dpp(
        0, __float_as_int(x), 0x138, 0xf, 0xf, true));
}
__device__ __forceinline__ float dr(float x) {   // lane i <- lane i+1, lane63 <- 0
    return __int_as_float(__builtin_amdgcn_update_dpp(
        0, __float_as_int(x), 0x130, 0xf, 0xf, true));
}

// Branch-free loads (verified R5/R7/R11). EDGE=false: raw unconditional loads.
// EDGE=true: clamp row + wave-uniform select (I=0, t_raw=-1 -> normalizes to 0).
template<bool EDGE>
__device__ __forceinline__ void load8t(const float* __restrict__ ip,
                                       const float* __restrict__ tp,
                                       int r, int c0, float* I, float* T) {
    const int rc = EDGE ? min(max(r, 0), IMG_H - 1) : r;
    const float* irow = ip + (ptrdiff_t)rc * IMG_W + c0;
    const float* trow = tp + (ptrdiff_t)rc * IMG_W + c0;
    float4 a = *(const float4*)(irow);
    float4 b = *(const float4*)(irow + 4);
    float4 c = *(const float4*)(trow);
    float4 d = *(const float4*)(trow + 4);
    I[0]=a.x; I[1]=a.y; I[2]=a.z; I[3]=a.w;
    I[4]=b.x; I[5]=b.y; I[6]=b.z; I[7]=b.w;
    T[0]=c.x; T[1]=c.y; T[2]=c.z; T[3]=c.w;
    T[4]=d.x; T[5]=d.y; T[6]=d.z; T[7]=d.w;
    if (EDGE) {
        const bool v = (r >= 0) && (r < IMG_H);   // wave-uniform
        #pragma unroll
        for (int j = 0; j < 8; ++j) {
            I[j] = v ? I[j] : 0.0f;
            T[j] = v ? T[j] : -1.0f;
        }
    }
}

// Vertical slides; T normalized at consume site (verified R4/R7/R10/R11).
__device__ __forceinline__ void slide_lead(const float* LI, const float* LTr,
                                           float* vI, float* vT, float* vII,
                                           float* vTT, float* vIT) {
    #pragma unroll
    for (int j = 0; j < 8; ++j) {
        float li = LI[j];
        float lt = fmaf(LTr[j], 0.5f, 0.5f);
        vI[j]  += li;
        vT[j]  += lt;
        vII[j]  = fmaf(li, li, vII[j]);
        vTT[j]  = fmaf(lt, lt, vTT[j]);
        vIT[j]  = fmaf(li, lt, vIT[j]);
    }
}

__device__ __forceinline__ void slide_full(const float* LI, const float* LTr,
                                           const float* QI, const float* QTr,
                                           float* vI, float* vT, float* vII,
                                           float* vTT, float* vIT) {
    #pragma unroll
    for (int j = 0; j < 8; ++j) {
        float li = LI[j], qi = QI[j];
        float lt = fmaf(LTr[j], 0.5f, 0.5f);
        float qt = fmaf(QTr[j], 0.5f, 0.5f);
        float dI = li - qi, aI = li + qi;
        float dT = lt - qt, aT = lt + qt;
        vI[j]  += dI;
        vT[j]  += dT;
        vII[j]  = fmaf(dI, aI, vII[j]);
        vTT[j]  = fmaf(dT, aT, vTT[j]);
        vIT[j]  = fmaf(li, lt, vIT[j] - qi * qt);
    }
}

__device__ __forceinline__ float cc_of(float sI, float sT, float sII, float sTT, float sIT) {
    const float inv81 = 1.0f / 81.0f;
    float u     = sI * inv81;
    float w     = sT * inv81;
    float cross = fmaf(-u, sT, sIT);
    float iv    = fmaf(-u, sI, sII);
    float tv    = fmaf(-w, sT, sTT);
    float den   = fmaf(tv, iv, 1e-5f);
    return cross * cross * __builtin_amdgcn_rcpf(den);
}

// Horizontal 9-tap sums + cc; inline DPP halos (verified R6/R7/R10/R11).
__device__ __forceinline__ float hphase(const float* vI, const float* vT,
                                        const float* vII, const float* vTT,
                                        const float* vIT) {
    float s0 = ((dl(vI [4])+dl(vI [5]))+(dl(vI [6])+dl(vI [7]))) + ((vI [0]+vI [1])+(vI [2]+vI [3])) + vI [4];
    float s1 = ((dl(vT [4])+dl(vT [5]))+(dl(vT [6])+dl(vT [7]))) + ((vT [0]+vT [1])+(vT [2]+vT [3])) + vT [4];
    float s2 = ((dl(vII[4])+dl(vII[5]))+(dl(vII[6])+dl(vII[7]))) + ((vII[0]+vII[1])+(vII[2]+vII[3])) + vII[4];
    float s3 = ((dl(vTT[4])+dl(vTT[5]))+(dl(vTT[6])+dl(vTT[7]))) + ((vTT[0]+vTT[1])+(vTT[2]+vTT[3])) + vTT[4];
    float s4 = ((dl(vIT[4])+dl(vIT[5]))+(dl(vIT[6])+dl(vIT[7]))) + ((vIT[0]+vIT[1])+(vIT[2]+vIT[3])) + vIT[4];
    float part = cc_of(s0, s1, s2, s3, s4);

    #define HSTEP(e0,e1,e2,e3,e4) \
        s0 += (e0); s1 += (e1); s2 += (e2); s3 += (e3); s4 += (e4); \
        part += cc_of(s0, s1, s2, s3, s4);

    HSTEP(vI[5]-dl(vI[4]), vT[5]-dl(vT[4]), vII[5]-dl(vII[4]), vTT[5]-dl(vTT[4]), vIT[5]-dl(vIT[4]))     // j=1
    HSTEP(vI[6]-dl(vI[5]), vT[6]-dl(vT[5]), vII[6]-dl(vII[5]), vTT[6]-dl(vTT[5]), vIT[6]-dl(vIT[5]))     // j=2
    HSTEP(vI[7]-dl(vI[6]), vT[7]-dl(vT[6]), vII[7]-dl(vII[6]), vTT[7]-dl(vTT[6]), vIT[7]-dl(vIT[6]))     // j=3
    HSTEP(dr(vI[0])-dl(vI[7]), dr(vT[0])-dl(vT[7]), dr(vII[0])-dl(vII[7]),
          dr(vTT[0])-dl(vTT[7]), dr(vIT[0])-dl(vIT[7]))                                                  // j=4
    HSTEP(dr(vI[1])-vI[0], dr(vT[1])-vT[0], dr(vII[1])-vII[0], dr(vTT[1])-vTT[0], dr(vIT[1])-vIT[0])     // j=5
    HSTEP(dr(vI[2])-vI[1], dr(vT[2])-vT[1], dr(vII[2])-vII[1], dr(vTT[2])-vTT[1], dr(vIT[2])-vIT[1])     // j=6
    HSTEP(dr(vI[3])-vI[2], dr(vT[3])-vT[2], dr(vII[3])-vII[2], dr(vTT[3])-vTT[2], dr(vIT[3])-vIT[2])     // j=7
    #undef HSTEP
    return part;
}

// Band body: COMPACT rolling loops (I$-resident, re-executed) + rotation-based
// distance-1 prefetch (R1-proven compile mode: tight VGPR, zero spill).
// Iter m=0..15: lead(m)=row r0+m-4; trail(m)=row r0+m-13 (m>=9, m=8 neutral);
// hphase on m=8..15 -> output rows r0..r0+7.
template<bool EDGE>
__device__ __forceinline__ float band_body(const float* __restrict__ ip,
                                           const float* __restrict__ tp,
                                           int r0, int c0) {
    float vI[8] = {}, vT[8] = {}, vII[8] = {}, vTT[8] = {}, vIT[8] = {};
    float acc = 0.0f;

    float cLI[8], cLT[8], nLI[8], nLT[8];    // lead: current / next (prefetch)
    float cQI[8], cQT[8], nQI[8], nQT[8];    // trail: current / next

    // ---- ramp: iters m=0..7 (rows r0-4..r0+3); ~1.4 KB body, 8 trips ----
    load8t<EDGE>(ip, tp, r0 - 4, c0, cLI, cLT);          // lead(0)
    #pragma unroll 1
    for (int m = 0; m < 8; ++m) {
        load8t<EDGE>(ip, tp, r0 - 3 + m, c0, nLI, nLT);  // lead(m+1); m=7 -> lead(8)
        slide_lead(cLI, cLT, vI, vT, vII, vTT, vIT);     // consume lead(m)
        #pragma unroll
        for (int j = 0; j < 8; ++j) { cLI[j] = nLI[j]; cLT[j] = nLT[j]; }
    }

    // neutral trail for m=8 (verified R6/R10): I=0, T_raw=-1 -> q terms = 0.
    #pragma unroll
    for (int j = 0; j < 8; ++j) { cQI[j] = 0.0f; cQT[j] = -1.0f; }

    // ---- hot: iters m=8..15; ~6 KB body, 8 trips, branch-free ----
    // (m=15 prefetches rows r0+12 / r0+3: dead but in-range for interior.)
    #pragma unroll 1
    for (int m = 8; m < 16; ++m) {
        load8t<EDGE>(ip, tp, r0 + m - 3,  c0, nLI, nLT); // lead(m+1)
        load8t<EDGE>(ip, tp, r0 + m - 12, c0, nQI, nQT); // trail(m+1)
        slide_full(cLI, cLT, cQI, cQT, vI, vT, vII, vTT, vIT); // consume iter m
        acc += hphase(vI, vT, vII, vTT, vIT);
        #pragma unroll
        for (int j = 0; j < 8; ++j) {
            cLI[j] = nLI[j]; cLT[j] = nLT[j];
            cQI[j] = nQI[j]; cQT[j] = nQT[j];
        }
    }
    return acc;
}

__global__ __launch_bounds__(256)      // no min-occupancy coercion (R6 lesson)
void cc_loss_kernel(const float* __restrict__ in, const float* __restrict__ tg,
                    float* __restrict__ out) {
    __shared__ float red[4];

    const int t    = threadIdx.x;
    const int w    = t >> 6;
    const int lane = t & 63;

    // XCD-chunked swizzle (verified R4/R10/R11).
    const int bid  = blockIdx.x;                       // 0..511
    const int bs   = (bid & 7) * 64 + (bid >> 3);      // bijective (512 % 8 == 0)

    const int gband = bs * 4 + w;              // 0..2047
    const int b     = gband >> 6;              // image (64 bands each)
    const int band  = gband & 63;
    const int r0    = band * ROWS;
    const size_t base = (size_t)b * (IMG_H * IMG_W);
    const float* ip = in + base;
    const float* tp = tg + base;
    const int c0    = lane * 8;                // own image cols c0..c0+7

    // Interior bands touch rows r0-4 .. r0+12 -> need 1 <= band <= 62.
    float acc;
    if (band >= 1 && band <= 62) acc = band_body<false>(ip, tp, r0, c0);
    else                         acc = band_body<true >(ip, tp, r0, c0);

    // ---- reduction: wave shuffle, one barrier per block, one atomic ----
    #pragma unroll
    for (int off = 32; off > 0; off >>= 1) acc += __shfl_down(acc, off, 64);
    if (lane == 0) red[w] = acc;
    __syncthreads();
    if (t == 0)
        atomicAdd(out, (red[0] + red[1] + red[2] + red[3]) * (-1.0f / NPIX));
}

extern "C" void kernel_launch(void* const* d_in, const int* in_sizes, int n_in,
                              void* d_out, int out_size, void* d_ws, size_t ws_size,
                              hipStream_t stream) {
    const float* in = (const float*)d_in[0];
    const float* tg = (const float*)d_in[1];
    float* out = (float*)d_out;

    hipMemsetAsync(out, 0, sizeof(float), stream);
    dim3 grid(N_IMG * BANDS / 4);              // 512 blocks x 4 wave-bands
    cc_loss_kernel<<<grid, 256, 0, stream>>>(in, tg, out);
}